// Round 4
// baseline (105.666 us; speedup 1.0000x reference)
//
#include <hip/hip_runtime.h>

// B=8, Na=Nb=4096, D=64. Top-3 NN by integer quantized coords (>>4, <128),
// weights 0.5-min(sqrt(d2)/128,0.5), weighted gather of b_feats,
// out = [a_feats | gathered] (B,Na,128) fp32.
//
// Exact-integer selection: d2 = |ca-cb|^2 < 2^16 exact; fp32 sqrt monotone &
// injective on these ints -> reference top-k order == integer d2 order with
// low-index tie-break.
//
// Rank by (d2 - |a|^2) = |b|^2 - 2 a.b (per-a-point constant shift):
//   G[i] = (|b_i|^2 << 12) | i                      (LDS, built once)
//   key  = G - (a.b)<<13
//        = mad(bz,-az*8192, mad(by,-ay*8192, mad(bx,-ax*8192, G)))
// three v_mad_i32_i24 (inline asm -- no reliance on sdot4 availability).
// Subtracted term is a multiple of 4096 -> low 12 bits stay == idx; signed
// min-3 of key == reference selection exactly (ties -> lower idx).
// Ranges: |ax<<13| < 2^20, products < 2^27, key in (-2^29, 2^28) -- all i32.
//
// Sorted-triple insert via med3 (3 ops):
//   k0'=min(k0,x); k1'=med3(k0,k1,x); k2'=med3(k1,k2,x)

#define NA 4096
#define NB 4096
#define FD 64
#define WPB 8                  // waves per block
#define MPW 4                  // a-points per wave
#define BLOCK (WPB * 64)
#define APB (WPB * MPW)        // 32 a-points per block -> grid 128 x 8 = 1024
                               // = exactly 4 blocks/CU resident, no tail

static __device__ __forceinline__ int med3_i32(int a, int b, int c) {
    int d;
    asm("v_med3_i32 %0, %1, %2, %3" : "=v"(d) : "v"(a), "v"(b), "v"(c));
    return d;
}

static __device__ __forceinline__ int mad_i24(int a, int b, int c) {
    int d;
    asm("v_mad_i32_i24 %0, %1, %2, %3" : "=v"(d) : "v"(a), "v"(b), "v"(c));
    return d;
}

__global__ __launch_bounds__(BLOCK, 8) void knn_gather_kernel(
    const float* __restrict__ a_feats,   // (B, NA, 64)
    const float* __restrict__ b_feats,   // (B, NB, 64)
    const int*   __restrict__ a_coords,  // (B, NA, 3)
    const int*   __restrict__ b_coords,  // (B, NB, 3)
    float* __restrict__ out)             // (B, NA, 128)
{
    __shared__ int2 s_pg[NB];            // {packed bxbybz, G} interleaved 8B

    const int batch = blockIdx.y;
    const int tid   = threadIdx.x;

    // ---- stage packed coords + G into LDS (32 KB) ----
    const int* bc = b_coords + (size_t)batch * NB * 3;
    for (int i = tid; i < NB; i += BLOCK) {
        const int x = bc[3 * i + 0] >> 4;
        const int y = bc[3 * i + 1] >> 4;
        const int z = bc[3 * i + 2] >> 4;
        int2 v;
        v.x = x | (y << 8) | (z << 16);
        v.y = ((__mul24(x, x) + __mul24(y, y) + __mul24(z, z)) << 12) | i;
        s_pg[i] = v;                      // ds_write_b64
    }
    __syncthreads();

    const int wave  = tid >> 6;
    const int lane  = tid & 63;
    const int nbase = blockIdx.x * APB + wave * MPW;

    // ---- per-wave a-point setup: m2a = -(coord << 13), aa = |a|^2 ----
    const int* ac = a_coords + ((size_t)batch * NA + nbase) * 3;
    int mx0, my0, mz0, mx1, my1, mz1, mx2, my2, mz2, mx3, my3, mz3;
    int aa0, aa1, aa2, aa3;
    {
        const int x0 = ac[0] >> 4, y0 = ac[1]  >> 4, z0 = ac[2]  >> 4;
        const int x1 = ac[3] >> 4, y1 = ac[4]  >> 4, z1 = ac[5]  >> 4;
        const int x2 = ac[6] >> 4, y2 = ac[7]  >> 4, z2 = ac[8]  >> 4;
        const int x3 = ac[9] >> 4, y3 = ac[10] >> 4, z3 = ac[11] >> 4;
        mx0 = -(x0 << 13); my0 = -(y0 << 13); mz0 = -(z0 << 13);
        mx1 = -(x1 << 13); my1 = -(y1 << 13); mz1 = -(z1 << 13);
        mx2 = -(x2 << 13); my2 = -(y2 << 13); mz2 = -(z2 << 13);
        mx3 = -(x3 << 13); my3 = -(y3 << 13); mz3 = -(z3 << 13);
        aa0 = __mul24(x0, x0) + __mul24(y0, y0) + __mul24(z0, z0);
        aa1 = __mul24(x1, x1) + __mul24(y1, y1) + __mul24(z1, z1);
        aa2 = __mul24(x2, x2) + __mul24(y2, y2) + __mul24(z2, z2);
        aa3 = __mul24(x3, x3) + __mul24(y3, y3) + __mul24(z3, z3);
    }

    int k0_0 = 0x7FFFFFFF, k1_0 = 0x7FFFFFFF, k2_0 = 0x7FFFFFFF;
    int k0_1 = 0x7FFFFFFF, k1_1 = 0x7FFFFFFF, k2_1 = 0x7FFFFFFF;
    int k0_2 = 0x7FFFFFFF, k1_2 = 0x7FFFFFFF, k2_2 = 0x7FFFFFFF;
    int k0_3 = 0x7FFFFFFF, k1_3 = 0x7FFFFFFF, k2_3 = 0x7FFFFFFF;

    // ---- hot loop: 16 iters x 4 candidates/lane (2 x ds_read_b128) ----
    const int4* pg4 = (const int4*)s_pg;   // int4 = 2 candidates {P,G,P,G}

#define KNN_PG(PP, GG)                                               \
    {                                                                \
        const int P  = (PP);                                         \
        const int G  = (GG);                                         \
        const int bx = P & 0xFF;                                     \
        const int by = (P >> 8) & 0xFF;                              \
        const int bz = P >> 16;                                      \
        {   const int u = mad_i24(bz, mz0,                           \
                          mad_i24(by, my0, mad_i24(bx, mx0, G)));    \
            const int n0 = min(k0_0, u);                             \
            const int n1 = med3_i32(k0_0, k1_0, u);                  \
            const int n2 = med3_i32(k1_0, k2_0, u);                  \
            k0_0 = n0; k1_0 = n1; k2_0 = n2; }                       \
        {   const int u = mad_i24(bz, mz1,                           \
                          mad_i24(by, my1, mad_i24(bx, mx1, G)));    \
            const int n0 = min(k0_1, u);                             \
            const int n1 = med3_i32(k0_1, k1_1, u);                  \
            const int n2 = med3_i32(k1_1, k2_1, u);                  \
            k0_1 = n0; k1_1 = n1; k2_1 = n2; }                       \
        {   const int u = mad_i24(bz, mz2,                           \
                          mad_i24(by, my2, mad_i24(bx, mx2, G)));    \
            const int n0 = min(k0_2, u);                             \
            const int n1 = med3_i32(k0_2, k1_2, u);                  \
            const int n2 = med3_i32(k1_2, k2_2, u);                  \
            k0_2 = n0; k1_2 = n1; k2_2 = n2; }                       \
        {   const int u = mad_i24(bz, mz3,                           \
                          mad_i24(by, my3, mad_i24(bx, mx3, G)));    \
            const int n0 = min(k0_3, u);                             \
            const int n1 = med3_i32(k0_3, k1_3, u);                  \
            const int n2 = med3_i32(k1_3, k2_3, u);                  \
            k0_3 = n0; k1_3 = n1; k2_3 = n2; }                       \
    }

#pragma unroll 2
    for (int k = 0; k < 16; ++k) {
        const int base = k << 7;                     // 128 int4-slots/iter
        const int4 X = pg4[base + lane];             // cands 2(base+lane)..+1
        const int4 Y = pg4[base + 64 + lane];
        KNN_PG(X.x, X.y)
        KNN_PG(X.z, X.w)
        KNN_PG(Y.x, Y.y)
        KNN_PG(Y.z, Y.w)
    }
#undef KNN_PG

    // ---- per a-point: butterfly merge + weighted gather + store ----
    const float* bfb = b_feats + (size_t)batch * NB * FD;
    int K0[MPW] = {k0_0, k0_1, k0_2, k0_3};
    int K1[MPW] = {k1_0, k1_1, k1_2, k1_3};
    int K2[MPW] = {k2_0, k2_1, k2_2, k2_3};
    const int AA[MPW] = {aa0, aa1, aa2, aa3};

#pragma unroll
    for (int m = 0; m < MPW; ++m) {
        int a0 = K0[m], a1 = K1[m], a2 = K2[m];
#pragma unroll
        for (int d = 1; d < 64; d <<= 1) {
            const int b0 = __shfl_xor(a0, d, 64);
            const int b1 = __shfl_xor(a1, d, 64);
            const int b2 = __shfl_xor(a2, d, 64);
            const int h0 = max(a0, b0);
            const int l1 = min(a1, b1);
            const int c2 = min(a2, b2);
            a0 = min(a0, b0);
            a1 = min(h0, l1);
            a2 = med3_i32(c2, l1, h0);   // = min(c2, max(l1,h0)), c2>=min(l1,h0)
        }
        const int i0 = a0 & 4095, i1 = a1 & 4095, i2 = a2 & 4095;
        const float d0 = sqrtf((float)((a0 >> 12) + AA[m])) * (1.0f / 128.0f);
        const float d1 = sqrtf((float)((a1 >> 12) + AA[m])) * (1.0f / 128.0f);
        const float d2 = sqrtf((float)((a2 >> 12) + AA[m])) * (1.0f / 128.0f);
        const float w0 = 0.5f - fminf(d0, 0.5f);
        const float w1 = 0.5f - fminf(d1, 0.5f);
        const float w2 = 0.5f - fminf(d2, 0.5f);

        const size_t row = (size_t)batch * NA + (nbase + m);
        const float g = w0 * bfb[i0 * FD + lane]
                      + w1 * bfb[i1 * FD + lane]
                      + w2 * bfb[i2 * FD + lane];
        out[row * 128 + lane]      = a_feats[row * FD + lane];
        out[row * 128 + 64 + lane] = g;
    }
}

extern "C" void kernel_launch(void* const* d_in, const int* in_sizes, int n_in,
                              void* d_out, int out_size, void* d_ws, size_t ws_size,
                              hipStream_t stream) {
    const float* a_feats  = (const float*)d_in[0];
    const float* b_feats  = (const float*)d_in[1];
    const int*   a_coords = (const int*)d_in[2];
    const int*   b_coords = (const int*)d_in[3];
    float* out = (float*)d_out;

    const int B = in_sizes[0] / (NA * FD);
    dim3 grid(NA / APB, B);
    knn_gather_kernel<<<grid, BLOCK, 0, stream>>>(a_feats, b_feats, a_coords,
                                                  b_coords, out);
}